// Round 6
// baseline (343.321 us; speedup 1.0000x reference)
//
#include <hip/hip_runtime.h>
#include <hip/hip_bf16.h>

// EncoderBlock: B=2, N=4096, D=256, H=8, HD=32, DFF=1024.
// I/O fp32; internal bf16 MFMA.
// Attention: barrier-free per-wave flash. K/V fragments loaded global->VGPR
// directly (no LDS staging, no __syncthreads); K prefetched one step ahead.
// No-max log2 softmax (scores bounded => exp2 fp32-safe). P round-trips
// wave-local LDS (C-layout -> A-layout), wave_barrier only.
#define Bb 2
#define Nn 4096
#define Dd 256
#define Hh 8
#define HDh 32
#define DFFd 1024
#define MT (Bb*Nn)   // 8192 rows
#define Tt ((size_t)MT * Dd)

typedef __attribute__((ext_vector_type(8))) short short8;
typedef __attribute__((ext_vector_type(4))) float f32x4;

__device__ __forceinline__ float bf2f(ushort u){
  union { unsigned int i; float f; } v; v.i = ((unsigned int)u) << 16; return v.f;
}
__device__ __forceinline__ ushort f2bf(float f){           // RNE
  union { float f; unsigned int i; } v; v.f = f;
  unsigned int r = v.i + 0x7fffu + ((v.i >> 16) & 1u);
  return (ushort)(r >> 16);
}
__device__ __forceinline__ ushort f2bff(float f){          // fast round (x>=0)
  union { float f; unsigned int i; } v; v.f = f;
  return (ushort)((v.i + 0x8000u) >> 16);
}

// ---- prep: fp32 weights -> bf16 transposed WT[n][k]; concat qkv bias -------
__global__ __launch_bounds__(256) void prep_kernel(
    const float* __restrict__ Wq, const float* __restrict__ Wk,
    const float* __restrict__ Wv, const float* __restrict__ Wo,
    const float* __restrict__ W1, const float* __restrict__ W2,
    const float* __restrict__ bq, const float* __restrict__ bk,
    const float* __restrict__ bv, ushort* __restrict__ wt,
    float* __restrict__ bqkv)
{
  if (blockIdx.x == 768) {
    const int t = threadIdx.x;
    bqkv[t] = bq[t]; bqkv[256 + t] = bk[t]; bqkv[512 + t] = bv[t];
    return;
  }
  const int base = (blockIdx.x * 256 + threadIdx.x) * 4;   // [0, 786432)
  const float* src; int k0, Ns;
  if (base < 196608) {                       // WTqkv[768][256]
    const int n = base >> 8; k0 = base & 255;
    const int w = n >> 8, cn = n & 255;
    src = (w == 0 ? Wq : w == 1 ? Wk : Wv) + cn; Ns = 256;
  } else if (base < 262144) {                // WTo[256][256]
    const int off = base - 196608;
    src = Wo + (off >> 8); k0 = off & 255; Ns = 256;
  } else if (base < 524288) {                // WT1[1024][256]
    const int off = base - 262144;
    src = W1 + (off >> 8); k0 = off & 255; Ns = 1024;
  } else {                                   // WT2[256][1024]
    const int off = base - 524288;
    src = W2 + (off >> 10); k0 = off & 1023; Ns = 256;
  }
  ushort4 o;
  o.x = f2bf(src[(size_t)(k0 + 0) * Ns]);
  o.y = f2bf(src[(size_t)(k0 + 1) * Ns]);
  o.z = f2bf(src[(size_t)(k0 + 2) * Ns]);
  o.w = f2bf(src[(size_t)(k0 + 3) * Ns]);
  *(ushort4*)(wt + base) = o;
}

// ---- LayerNorm: (x-mean)/(std+1e-6); fp32 in, bf16 out; wave per row -------
__global__ __launch_bounds__(256) void ln_kernel(const float* __restrict__ x,
                                                 ushort* __restrict__ out)
{
  const int wave = threadIdx.x >> 6, lane = threadIdx.x & 63;
  const int row = blockIdx.x * 4 + wave;
  const float4 u = *(const float4*)(x + (size_t)row * Dd + lane * 4);
  float s1 = u.x + u.y + u.z + u.w;
  float s2 = u.x*u.x + u.y*u.y + u.z*u.z + u.w*u.w;
  #pragma unroll
  for (int m = 1; m < 64; m <<= 1) { s1 += __shfl_xor(s1, m, 64); s2 += __shfl_xor(s2, m, 64); }
  const float mean = s1 * (1.0f / Dd);
  float var = s2 * (1.0f / Dd) - mean * mean;
  var = var < 0.f ? 0.f : var;
  const float inv = 1.0f / (sqrtf(var) + 1e-6f);
  ushort4 o;
  o.x = f2bf((u.x - mean) * inv); o.y = f2bf((u.y - mean) * inv);
  o.z = f2bf((u.z - mean) * inv); o.w = f2bf((u.w - mean) * inv);
  *(ushort4*)(out + (size_t)row * Dd + lane * 4) = o;
}

// ---- BMx64-tile MFMA GEMM, LDS double-buffer, ONE barrier per k-step -------
// write regs->LDS[p]; barrier; issue next-step global->reg prefetch (lands
// during MFMA phase, consumed before next barrier); ds_read+MFMA from LDS[p].
// EPI 0: QKV fused (N=768): q scaled by log2e/sqrt(32), q/k -> [b,h,n,hd],
//        v -> transposed [b,h,hd,n]
// EPI 1: + fp32 residual, fp32 out
// EPI 2: gelu(tanh), bf16 out
template<int EPI, int BM>
__global__ __launch_bounds__(256) void gemm_epi(
    const ushort* __restrict__ A, const ushort* __restrict__ BT,
    const float* __restrict__ bias, const float* __restrict__ res,
    void* __restrict__ outv, int N, int K)
{
  constexpr int MI = BM / 64;                  // A int4-loads per thread
  __shared__ __align__(16) ushort As[2][BM][32];
  __shared__ __align__(16) ushort Bs[2][64][32];
  const int tid = threadIdx.x;
  const int wave = tid >> 6, lane = tid & 63;
  const int quad = lane >> 4, l15 = lane & 15;
  const int n0 = blockIdx.x * 64, m0 = blockIdx.y * BM;
  f32x4 acc[MI][4];
  #pragma unroll
  for (int mt = 0; mt < MI; mt++)
    #pragma unroll
    for (int nt = 0; nt < 4; nt++) acc[mt][nt] = (f32x4){0.f,0.f,0.f,0.f};
  // staging map: int4 #i -> row i>>2, ushort col (i&3)*8
  int4 ra[MI], rb;
  #pragma unroll
  for (int mi = 0; mi < MI; mi++) {
    const int i = tid + mi * 256;
    ra[mi] = *(const int4*)(A + (size_t)(m0 + (i >> 2)) * K + (i & 3) * 8);
  }
  rb = *(const int4*)(BT + (size_t)(n0 + (tid >> 2)) * K + (tid & 3) * 8);
  int p = 0;
  for (int k0 = 0; k0 < K; k0 += 32) {
    #pragma unroll
    for (int mi = 0; mi < MI; mi++) {
      const int i = tid + mi * 256;
      *(int4*)(&As[p][i >> 2][(i & 3) * 8]) = ra[mi];
    }
    *(int4*)(&Bs[p][tid >> 2][(tid & 3) * 8]) = rb;
    __syncthreads();
    const int kn = (k0 + 32 < K) ? k0 + 32 : 0;   // wrapped prefetch (harmless)
    #pragma unroll
    for (int mi = 0; mi < MI; mi++) {
      const int i = tid + mi * 256;
      ra[mi] = *(const int4*)(A + (size_t)(m0 + (i >> 2)) * K + kn + (i & 3) * 8);
    }
    rb = *(const int4*)(BT + (size_t)(n0 + (tid >> 2)) * K + kn + (tid & 3) * 8);
    short8 af[MI];
    #pragma unroll
    for (int mt = 0; mt < MI; mt++)
      af[mt] = *(const short8*)(&As[p][wave * (16 * MI) + mt * 16 + l15][quad * 8]);
    #pragma unroll
    for (int nt = 0; nt < 4; nt++) {
      const short8 bf = *(const short8*)(&Bs[p][nt * 16 + l15][quad * 8]);
      #pragma unroll
      for (int mt = 0; mt < MI; mt++)
        acc[mt][nt] = __builtin_amdgcn_mfma_f32_16x16x32_bf16(af[mt], bf, acc[mt][nt], 0, 0, 0);
    }
    p ^= 1;
  }
  #pragma unroll
  for (int mt = 0; mt < MI; mt++) {
    const int row0 = m0 + wave * (16 * MI) + mt * 16 + quad * 4;
    #pragma unroll
    for (int nt = 0; nt < 4; nt++) {
      const int col = n0 + nt * 16 + l15;
      const float bv = bias[col];
      float c[4];
      #pragma unroll
      for (int i = 0; i < 4; i++) c[i] = acc[mt][nt][i] + bv;
      if (EPI == 0) {
        ushort* qkv = (ushort*)outv;
        const int w = col >> 8, cd = col & 255;
        const int h = cd >> 5, hd = cd & 31;
        const int b = row0 >> 12, n = row0 & (Nn - 1);
        if (w < 2) {
          const float sc = (w == 0) ? (1.4426950408889634f * 0.17677669529663687f) : 1.0f;
          ushort* dst = qkv + (size_t)w * Tt + ((size_t)((b * Hh + h) * Nn) + n) * HDh + hd;
          #pragma unroll
          for (int i = 0; i < 4; i++) dst[(size_t)i * HDh] = f2bf(c[i] * sc);
        } else {   // V transposed: [b,h,hd,n]
          ushort4 pk;
          pk.x = f2bf(c[0]); pk.y = f2bf(c[1]); pk.z = f2bf(c[2]); pk.w = f2bf(c[3]);
          *(ushort4*)(qkv + 2 * Tt + ((size_t)((b * Hh + h) * HDh + hd)) * Nn + n) = pk;
        }
      } else if (EPI == 1) {
        float* out = (float*)outv;
        #pragma unroll
        for (int i = 0; i < 4; i++) {
          const size_t idx = (size_t)(row0 + i) * N + col;
          out[idx] = c[i] + res[idx];
        }
      } else {
        ushort* out = (ushort*)outv;
        #pragma unroll
        for (int i = 0; i < 4; i++) {
          const float t = tanhf(0.7978845608028654f * (c[i] + 0.044715f * c[i] * c[i] * c[i]));
          out[(size_t)(row0 + i) * N + col] = f2bf(0.5f * c[i] * (1.0f + t));
        }
      }
    }
  }
}

// ---- Flash attention, barrier-free: S^T = K Q^T (Q pre-scaled), p = exp2(s),
// O^T += V^T P^T. K frags prefetched 1 step ahead; V frags loaded at step top.
// Only LDS use: wave-local P round-trip + final O transpose. ------------------
__global__ __launch_bounds__(256) void attn_kernel(
    const ushort* __restrict__ qp, const ushort* __restrict__ kp,
    const ushort* __restrict__ vtg, ushort* __restrict__ out)
{
  __shared__ __align__(16) ushort Ps[4][16][72];   // per-wave P^T [q][kv]
  const int tid = threadIdx.x;
  const int wave = tid >> 6, lane = tid & 63;
  const int quad = lane >> 4, l15 = lane & 15;
  const int bh = blockIdx.x, qt = blockIdx.y;      // bh fastest -> L2 locality
  const size_t base = (size_t)bh * Nn * HDh;
  const int qrow = qt * 64 + wave * 16 + l15;
  const short8 qf = *(const short8*)(qp + base + (size_t)qrow * HDh + quad * 8);
  const ushort* kb = kp + base + (size_t)(l15)*HDh + quad * 8;   // + (kv0+nt*16)*32
  const ushort* vb0 = vtg + base + (size_t)l15 * Nn + quad * 8;        // d-tile 0
  const ushort* vb1 = vtg + base + (size_t)(16 + l15) * Nn + quad * 8; // d-tile 1
  f32x4 o0 = {0.f,0.f,0.f,0.f}, o1 = {0.f,0.f,0.f,0.f};   // O^T: d=quad*4+i(+16), q=l15
  float rs = 0.f;
  const f32x4 zero4 = {0.f,0.f,0.f,0.f};
  short8 kf[4], kn[4], vf[4];
  #pragma unroll
  for (int nt = 0; nt < 4; nt++)
    kf[nt] = *(const short8*)(kb + (size_t)(nt * 16) * HDh);
  for (int step = 0; step < Nn / 64; step++) {
    const int kv0 = step * 64;
    // V for current step (lands during S + softmax)
    vf[0] = *(const short8*)(vb0 + kv0);
    vf[1] = *(const short8*)(vb0 + kv0 + 32);
    vf[2] = *(const short8*)(vb1 + kv0);
    vf[3] = *(const short8*)(vb1 + kv0 + 32);
    // S^T[kv][q] from prefetched K frags
    f32x4 s[4];
    #pragma unroll
    for (int nt = 0; nt < 4; nt++)
      s[nt] = __builtin_amdgcn_mfma_f32_16x16x32_bf16(kf[nt], qf, zero4, 0, 0, 0);
    // prefetch K for next step (full step to land; wrapped on last)
    const int kvn = ((step + 1) & (Nn / 64 - 1)) * 64;
    #pragma unroll
    for (int nt = 0; nt < 4; nt++)
      kn[nt] = *(const short8*)(kb + (size_t)(kvn + nt * 16) * HDh);
    // softmax (no max: scores bounded), pack to bf16, store P^T wave-local
    #pragma unroll
    for (int nt = 0; nt < 4; nt++) {
      const float p0 = __builtin_amdgcn_exp2f(s[nt][0]);
      const float p1 = __builtin_amdgcn_exp2f(s[nt][1]);
      const float p2 = __builtin_amdgcn_exp2f(s[nt][2]);
      const float p3 = __builtin_amdgcn_exp2f(s[nt][3]);
      rs += (p0 + p1) + (p2 + p3);
      const unsigned int u0 = __float_as_uint(p0) + 0x8000u;
      const unsigned int u1 = __float_as_uint(p1) + 0x8000u;
      const unsigned int u2 = __float_as_uint(p2) + 0x8000u;
      const unsigned int u3 = __float_as_uint(p3) + 0x8000u;
      uint2 pk;
      pk.x = __builtin_amdgcn_perm(u1, u0, 0x07060302u);
      pk.y = __builtin_amdgcn_perm(u3, u2, 0x07060302u);
      *(uint2*)(&Ps[wave][l15][nt * 16 + quad * 4]) = pk;
    }
    __builtin_amdgcn_wave_barrier();   // wave-local LDS; DS ops in-order per wave
    // O^T += V^T P^T (two kv-halves)
    const short8 pf0 = *(const short8*)(&Ps[wave][l15][quad * 8]);
    const short8 pf1 = *(const short8*)(&Ps[wave][l15][32 + quad * 8]);
    o0 = __builtin_amdgcn_mfma_f32_16x16x32_bf16(vf[0], pf0, o0, 0, 0, 0);
    o1 = __builtin_amdgcn_mfma_f32_16x16x32_bf16(vf[2], pf0, o1, 0, 0, 0);
    o0 = __builtin_amdgcn_mfma_f32_16x16x32_bf16(vf[1], pf1, o0, 0, 0, 0);
    o1 = __builtin_amdgcn_mfma_f32_16x16x32_bf16(vf[3], pf1, o1, 0, 0, 0);
    __builtin_amdgcn_wave_barrier();
    #pragma unroll
    for (int nt = 0; nt < 4; nt++) kf[nt] = kn[nt];
  }
  // l reduction across quads (lanes share q=l15)
  rs += __shfl_xor(rs, 16, 64);
  rs += __shfl_xor(rs, 32, 64);
  const float inv = 1.0f / rs;
  // transpose O^T -> O rows via wave-local scratch, 16B coalesced stores
  ushort* Os = &Ps[wave][0][0];                    // view as [16][40]
  #pragma unroll
  for (int i = 0; i < 4; i++) {
    Os[l15 * 40 + quad * 4 + i]      = f2bff(o0[i] * inv);
    Os[l15 * 40 + 16 + quad * 4 + i] = f2bff(o1[i] * inv);
  }
  __builtin_amdgcn_wave_barrier();
  const int rq = lane >> 2, c4 = lane & 3;
  const short8 ov = *(const short8*)(Os + rq * 40 + c4 * 8);
  const int b = bh >> 3, h = bh & 7;
  const int n = qt * 64 + wave * 16 + rq;
  *(short8*)(out + ((size_t)(b * Nn + n)) * Dd + h * HDh + c4 * 8) = ov;
}

extern "C" void kernel_launch(void* const* d_in, const int* in_sizes, int n_in,
                              void* d_out, int out_size, void* d_ws, size_t ws_size,
                              hipStream_t stream)
{
  const float* x  = (const float*)d_in[0];
  const float* Wq = (const float*)d_in[1];
  const float* bq = (const float*)d_in[2];
  const float* Wk = (const float*)d_in[3];
  const float* bk = (const float*)d_in[4];
  const float* Wv = (const float*)d_in[5];
  const float* bv = (const float*)d_in[6];
  const float* Wo = (const float*)d_in[7];
  const float* bo = (const float*)d_in[8];
  const float* W1 = (const float*)d_in[9];
  const float* b1 = (const float*)d_in[10];
  const float* W2 = (const float*)d_in[11];
  const float* b2 = (const float*)d_in[12];

  char* ws = (char*)d_ws;
  ushort* wt    = (ushort*)ws;                       // 786432 bf16
  ushort* wtqkv = wt;
  ushort* wto   = wt + 196608;
  ushort* wt1   = wt + 262144;
  ushort* wt2   = wt + 524288;
  float*  bqkv  = (float*)(ws + 786432 * 2);
  ushort* s0    = (ushort*)(ws + 786432 * 2 + 4096); // 4 MiB slots
  ushort* s1    = s0 + Tt;                           // q [b,h,n,hd] (scaled)
  ushort* s2    = s1 + Tt;                           // k [b,h,n,hd]
  ushort* s3    = s2 + Tt;                           // v [b,h,hd,n]
  float*  xsk   = (float*)(s3 + Tt);                 // fp32 8 MiB
  ushort* xn2   = (ushort*)(xsk + Tt);               // bf16 4 MiB
  ushort* xn1   = s0;
  ushort* attn  = s0;                                // reuse (xn1 dead)
  ushort* hid   = s0;                                // 16 MiB spans s0..s3
  float*  outp  = (float*)d_out;

  const dim3 blk(256);
  hipLaunchKernelGGL(prep_kernel, dim3(769), blk, 0, stream,
                     Wq, Wk, Wv, Wo, W1, W2, bq, bk, bv, wt, bqkv);
  hipLaunchKernelGGL(ln_kernel, dim3(MT / 4), blk, 0, stream, x, xn1);
  hipLaunchKernelGGL((gemm_epi<0,128>), dim3(12, 64), blk, 0, stream,
                     xn1, wtqkv, bqkv, (const float*)nullptr, (void*)s1, 768, Dd);

  hipLaunchKernelGGL(attn_kernel, dim3(Bb * Hh, Nn / 64), blk, 0, stream,
                     s1, s2, s3, attn);

  hipLaunchKernelGGL((gemm_epi<1,64>), dim3(4, 128), blk, 0, stream,
                     attn, wto, bo, x, (void*)xsk, Dd, Dd);
  hipLaunchKernelGGL(ln_kernel, dim3(MT / 4), blk, 0, stream, xsk, xn2);
  hipLaunchKernelGGL((gemm_epi<2,128>), dim3(16, 64), blk, 0, stream,
                     xn2, wt1, b1, (const float*)nullptr, (void*)hid, DFFd, Dd);
  hipLaunchKernelGGL((gemm_epi<1,64>), dim3(4, 128), blk, 0, stream,
                     hid, wt2, b2, xsk, (void*)outp, Dd, DFFd);
}

// Round 7
// 231.732 us; speedup vs baseline: 1.4815x; 1.4815x over previous
//
#include <hip/hip_runtime.h>
#include <hip/hip_bf16.h>

// EncoderBlock: B=2, N=4096, D=256, H=8, HD=32, DFF=1024.
// I/O fp32; internal bf16 MFMA.
// Attention: LDS-staged flash, double-buffered K(gll16)/V(reg), ONE barrier
// per 64-kv step with prefetch issued a full compute phase before its drain.
// q-block 128 (wave=32 q rows). No-max log2 softmax (scores bounded).
#define Bb 2
#define Nn 4096
#define Dd 256
#define Hh 8
#define HDh 32
#define DFFd 1024
#define MT (Bb*Nn)   // 8192 rows
#define Tt ((size_t)MT * Dd)
#define NS (Nn / 64) // kv steps

typedef __attribute__((ext_vector_type(8))) short short8;
typedef __attribute__((ext_vector_type(4))) float f32x4;
typedef __attribute__((address_space(1))) const unsigned int gu32;
typedef __attribute__((address_space(3))) unsigned int lu32;

__device__ __forceinline__ void gll16(const ushort* g, ushort* l) {
  // async global->LDS, 16B/lane; LDS dest = wave-uniform base + lane*16
  __builtin_amdgcn_global_load_lds((gu32*)g, (lu32*)l, 16, 0, 0);
}
__device__ __forceinline__ ushort f2bf(float f){           // RNE
  union { float f; unsigned int i; } v; v.f = f;
  unsigned int r = v.i + 0x7fffu + ((v.i >> 16) & 1u);
  return (ushort)(r >> 16);
}
__device__ __forceinline__ ushort f2bff(float f){          // fast round (x>=0)
  union { float f; unsigned int i; } v; v.f = f;
  return (ushort)((v.i + 0x8000u) >> 16);
}

// ---- prep: LDS-tiled transpose fp32 W -> bf16 WT[n][k]; concat qkv bias ----
// 64x64 tiles; 192 tile-blocks + 1 bias block.
__global__ __launch_bounds__(256) void prep_kernel(
    const float* __restrict__ Wq, const float* __restrict__ Wk,
    const float* __restrict__ Wv, const float* __restrict__ Wo,
    const float* __restrict__ W1, const float* __restrict__ W2,
    const float* __restrict__ bq, const float* __restrict__ bk,
    const float* __restrict__ bv, ushort* __restrict__ wt,
    float* __restrict__ bqkv)
{
  const int bid = blockIdx.x, t = threadIdx.x;
  if (bid == 192) {
    bqkv[t] = bq[t]; bqkv[256 + t] = bk[t]; bqkv[512 + t] = bv[t];
    return;
  }
  __shared__ __align__(16) ushort T[64][72];
  const float* src; ushort* dst; int Nsrc, Kdst, kt, nt;
  if (bid < 64) {
    const int m = bid >> 4, tile = bid & 15;
    kt = tile >> 2; nt = tile & 3; Nsrc = 256; Kdst = 256;
    src = (m == 0 ? Wq : m == 1 ? Wk : m == 2 ? Wv : Wo);
    dst = (m == 3) ? (wt + 196608) : (wt + m * 65536);   // wto | wtqkv rows
  } else if (bid < 128) {
    const int tile = bid - 64; kt = tile >> 4; nt = tile & 15;
    Nsrc = 1024; Kdst = 256; src = W1; dst = wt + 262144;
  } else {
    const int tile = bid - 128; kt = tile >> 2; nt = tile & 3;
    Nsrc = 256; Kdst = 1024; src = W2; dst = wt + 524288;
  }
  const int k0 = kt * 64, n0 = nt * 64;
  const int cc = t & 15, rr = t >> 4;
  #pragma unroll
  for (int pass = 0; pass < 4; pass++) {
    const int k = rr + pass * 16;
    const float4 v = *(const float4*)(src + (size_t)(k0 + k) * Nsrc + n0 + cc * 4);
    T[cc * 4 + 0][k] = f2bf(v.x); T[cc * 4 + 1][k] = f2bf(v.y);
    T[cc * 4 + 2][k] = f2bf(v.z); T[cc * 4 + 3][k] = f2bf(v.w);
  }
  __syncthreads();
  const int nl = t >> 2, ks = (t & 3) * 16;
  const short8 a = *(const short8*)(&T[nl][ks]);
  const short8 b = *(const short8*)(&T[nl][ks + 8]);
  ushort* drow = dst + (size_t)(n0 + nl) * Kdst + k0 + ks;
  *(short8*)(drow) = a; *(short8*)(drow + 8) = b;
}

// ---- LayerNorm: (x-mean)/(std+1e-6); fp32 in, bf16 out; wave per row -------
__global__ __launch_bounds__(256) void ln_kernel(const float* __restrict__ x,
                                                 ushort* __restrict__ out)
{
  const int wave = threadIdx.x >> 6, lane = threadIdx.x & 63;
  const int row = blockIdx.x * 4 + wave;
  const float4 u = *(const float4*)(x + (size_t)row * Dd + lane * 4);
  float s1 = u.x + u.y + u.z + u.w;
  float s2 = u.x*u.x + u.y*u.y + u.z*u.z + u.w*u.w;
  #pragma unroll
  for (int m = 1; m < 64; m <<= 1) { s1 += __shfl_xor(s1, m, 64); s2 += __shfl_xor(s2, m, 64); }
  const float mean = s1 * (1.0f / Dd);
  float var = s2 * (1.0f / Dd) - mean * mean;
  var = var < 0.f ? 0.f : var;
  const float inv = 1.0f / (sqrtf(var) + 1e-6f);
  ushort4 o;
  o.x = f2bf((u.x - mean) * inv); o.y = f2bf((u.y - mean) * inv);
  o.z = f2bf((u.z - mean) * inv); o.w = f2bf((u.w - mean) * inv);
  *(ushort4*)(out + (size_t)row * Dd + lane * 4) = o;
}

// ---- BMx64-tile MFMA GEMM, gll16 double-buffer, ONE barrier per k-step -----
// Loop: issue gll16(k+32)->LDS[p^1]; ds_read+MFMA from LDS[p]; barrier
// (the vmcnt drain at the barrier is covered by the MFMA phase).
// EPI 0: QKV fused (N=768): q scaled by log2e/sqrt(32), q/k -> [b,h,n,hd],
//        v -> transposed [b,h,hd,n].  EPI 1: +fp32 residual.  EPI 2: gelu.
template<int EPI, int BM>
__global__ __launch_bounds__(256) void gemm_epi(
    const ushort* __restrict__ A, const ushort* __restrict__ BT,
    const float* __restrict__ bias, const float* __restrict__ res,
    void* __restrict__ outv, int N, int K)
{
  constexpr int MI = BM / 64;
  __shared__ __align__(16) ushort As[2][BM][32];
  __shared__ __align__(16) ushort Bs[2][64][32];
  const int tid = threadIdx.x;
  const int wave = tid >> 6, lane = tid & 63;
  const int quad = lane >> 4, l15 = lane & 15;
  const int n0 = blockIdx.x * 64, m0 = blockIdx.y * BM;
  f32x4 acc[MI][4];
  #pragma unroll
  for (int mt = 0; mt < MI; mt++)
    #pragma unroll
    for (int nt = 0; nt < 4; nt++) acc[mt][nt] = (f32x4){0.f,0.f,0.f,0.f};
  const int sr = lane >> 2, sc = (lane & 3) * 8;
  const ushort* ag0 = A + (size_t)(m0 + wave * 16 + sr) * K + sc;
  const ushort* ag1 = A + (size_t)(m0 + 64 + wave * 16 + sr) * K + sc;  // MI==2 only
  const ushort* bg  = BT + (size_t)(n0 + wave * 16 + sr) * K + sc;
  gll16(ag0, &As[0][wave * 16][0]);
  if (MI == 2) gll16(ag1, &As[0][64 + wave * 16][0]);
  gll16(bg, &Bs[0][wave * 16][0]);
  __syncthreads();
  int p = 0;
  for (int k0 = 0; k0 < K; k0 += 32) {
    if (k0 + 32 < K) {
      gll16(ag0 + k0 + 32, &As[p ^ 1][wave * 16][0]);
      if (MI == 2) gll16(ag1 + k0 + 32, &As[p ^ 1][64 + wave * 16][0]);
      gll16(bg + k0 + 32, &Bs[p ^ 1][wave * 16][0]);
    }
    short8 af[MI];
    #pragma unroll
    for (int mt = 0; mt < MI; mt++)
      af[mt] = *(const short8*)(&As[p][wave * (16 * MI) + mt * 16 + l15][quad * 8]);
    #pragma unroll
    for (int nt = 0; nt < 4; nt++) {
      const short8 bf = *(const short8*)(&Bs[p][nt * 16 + l15][quad * 8]);
      #pragma unroll
      for (int mt = 0; mt < MI; mt++)
        acc[mt][nt] = __builtin_amdgcn_mfma_f32_16x16x32_bf16(af[mt], bf, acc[mt][nt], 0, 0, 0);
    }
    __syncthreads();
    p ^= 1;
  }
  #pragma unroll
  for (int mt = 0; mt < MI; mt++) {
    const int row0 = m0 + wave * (16 * MI) + mt * 16 + quad * 4;
    #pragma unroll
    for (int nt = 0; nt < 4; nt++) {
      const int col = n0 + nt * 16 + l15;
      const float bv = bias[col];
      float c[4];
      #pragma unroll
      for (int i = 0; i < 4; i++) c[i] = acc[mt][nt][i] + bv;
      if (EPI == 0) {
        ushort* qkv = (ushort*)outv;
        const int w = col >> 8, cd = col & 255;
        const int h = cd >> 5, hd = cd & 31;
        const int b = row0 >> 12, n = row0 & (Nn - 1);
        if (w < 2) {
          const float sc2 = (w == 0) ? (1.4426950408889634f * 0.17677669529663687f) : 1.0f;
          ushort* dst = qkv + (size_t)w * Tt + ((size_t)((b * Hh + h) * Nn) + n) * HDh + hd;
          #pragma unroll
          for (int i = 0; i < 4; i++) dst[(size_t)i * HDh] = f2bf(c[i] * sc2);
        } else {   // V transposed: [b,h,hd,n]
          ushort4 pk;
          pk.x = f2bf(c[0]); pk.y = f2bf(c[1]); pk.z = f2bf(c[2]); pk.w = f2bf(c[3]);
          *(ushort4*)(qkv + 2 * Tt + ((size_t)((b * Hh + h) * HDh + hd)) * Nn + n) = pk;
        }
      } else if (EPI == 1) {
        float* out = (float*)outv;
        #pragma unroll
        for (int i = 0; i < 4; i++) {
          const size_t idx = (size_t)(row0 + i) * N + col;
          out[idx] = c[i] + res[idx];
        }
      } else {
        ushort* out = (ushort*)outv;
        #pragma unroll
        for (int i = 0; i < 4; i++) {
          const float t = tanhf(0.7978845608028654f * (c[i] + 0.044715f * c[i] * c[i] * c[i]));
          out[(size_t)(row0 + i) * N + col] = f2bf(0.5f * c[i] * (1.0f + t));
        }
      }
    }
  }
}

// ---- Flash attention: q-block 128 (wave=32 q), 64-kv steps, double-buffered
// K (gll16) and V^T (reg-staged, padded). S^T = K Q^T, p = exp2(s),
// O^T += V^T P^T.  One __syncthreads per step. --------------------------------
__global__ __launch_bounds__(256) void attn_kernel(
    const ushort* __restrict__ qp, const ushort* __restrict__ kp,
    const ushort* __restrict__ vtg, ushort* __restrict__ out)
{
  __shared__ __align__(16) ushort Ks[2][64][32];   // K tile [kv][d] (gll16 dest)
  __shared__ __align__(16) ushort Vt[2][32][72];   // V^T tile [d][kv], padded
  __shared__ __align__(16) ushort Ps[4][32][72];   // per-wave P [q][kv]
  const int tid = threadIdx.x;
  const int wave = tid >> 6, lane = tid & 63;
  const int quad = lane >> 4, l15 = lane & 15;
  const int qt = blockIdx.x, bh = blockIdx.y;
  const size_t base = (size_t)bh * Nn * HDh;
  const int q0 = qt * 128 + wave * 32;
  const short8 qf0 = *(const short8*)(qp + base + (size_t)(q0 + l15) * HDh + quad * 8);
  const short8 qf1 = *(const short8*)(qp + base + (size_t)(q0 + 16 + l15) * HDh + quad * 8);
  const ushort* kg = kp + base + (size_t)(tid >> 2) * HDh + (lane & 3) * 8;  // +kv0*HDh
  const int vr = tid >> 3, vc = (tid & 7) * 8;
  const ushort* vg = vtg + base + (size_t)vr * Nn + vc;                      // +kv0
  f32x4 o00 = {0,0,0,0}, o01 = {0,0,0,0}, o10 = {0,0,0,0}, o11 = {0,0,0,0};
  float rs0 = 0.f, rs1 = 0.f;
  const f32x4 zero4 = {0,0,0,0};
  // preamble: stage step0; prefetch step1 V to regs (K step1 gll16'd in iter 0)
  gll16(kg, &Ks[0][wave * 16][0]);
  int4 vreg = *(const int4*)vg;
  *(int4*)(&Vt[0][vr][vc]) = vreg;
  vreg = *(const int4*)(vg + 64);
  __syncthreads();
  for (int step = 0; step < NS; step++) {
    const int p = step & 1;
    if (step + 1 < NS) {
      gll16(kg + (size_t)(step + 1) * 64 * HDh, &Ks[p ^ 1][wave * 16][0]);
      *(int4*)(&Vt[p ^ 1][vr][vc]) = vreg;
    }
    if (step + 2 < NS) vreg = *(const int4*)(vg + (size_t)(step + 2) * 64);
    // S^T[kv][q] for both q-tiles
    f32x4 s0[4], s1[4];
    #pragma unroll
    for (int nt = 0; nt < 4; nt++) {
      const short8 kf = *(const short8*)(&Ks[p][nt * 16 + l15][quad * 8]);
      s0[nt] = __builtin_amdgcn_mfma_f32_16x16x32_bf16(kf, qf0, zero4, 0, 0, 0);
      s1[nt] = __builtin_amdgcn_mfma_f32_16x16x32_bf16(kf, qf1, zero4, 0, 0, 0);
    }
    // softmax (no max) + pack P as bf16 rows [q][kv]
    #pragma unroll
    for (int nt = 0; nt < 4; nt++) {
      const float a0 = __builtin_amdgcn_exp2f(s0[nt][0]);
      const float a1 = __builtin_amdgcn_exp2f(s0[nt][1]);
      const float a2 = __builtin_amdgcn_exp2f(s0[nt][2]);
      const float a3 = __builtin_amdgcn_exp2f(s0[nt][3]);
      rs0 += (a0 + a1) + (a2 + a3);
      uint2 pk;
      pk.x = __builtin_amdgcn_perm(__float_as_uint(a1) + 0x8000u,
                                   __float_as_uint(a0) + 0x8000u, 0x07060302u);
      pk.y = __builtin_amdgcn_perm(__float_as_uint(a3) + 0x8000u,
                                   __float_as_uint(a2) + 0x8000u, 0x07060302u);
      *(uint2*)(&Ps[wave][l15][nt * 16 + quad * 4]) = pk;
      const float b0 = __builtin_amdgcn_exp2f(s1[nt][0]);
      const float b1 = __builtin_amdgcn_exp2f(s1[nt][1]);
      const float b2 = __builtin_amdgcn_exp2f(s1[nt][2]);
      const float b3 = __builtin_amdgcn_exp2f(s1[nt][3]);
      rs1 += (b0 + b1) + (b2 + b3);
      uint2 qk2;
      qk2.x = __builtin_amdgcn_perm(__float_as_uint(b1) + 0x8000u,
                                    __float_as_uint(b0) + 0x8000u, 0x07060302u);
      qk2.y = __builtin_amdgcn_perm(__float_as_uint(b3) + 0x8000u,
                                    __float_as_uint(b2) + 0x8000u, 0x07060302u);
      *(uint2*)(&Ps[wave][16 + l15][nt * 16 + quad * 4]) = qk2;
    }
    __builtin_amdgcn_wave_barrier();   // wave-local LDS; DS in-order per wave
    // O^T += V^T P^T  (2 kv-chunks x 2 d-tiles x 2 q-tiles)
    #pragma unroll
    for (int c = 0; c < 2; c++) {
      const short8 v0 = *(const short8*)(&Vt[p][l15][c * 32 + quad * 8]);
      const short8 v1 = *(const short8*)(&Vt[p][16 + l15][c * 32 + quad * 8]);
      const short8 pb0 = *(const short8*)(&Ps[wave][l15][c * 32 + quad * 8]);
      const short8 pb1 = *(const short8*)(&Ps[wave][16 + l15][c * 32 + quad * 8]);
      o00 = __builtin_amdgcn_mfma_f32_16x16x32_bf16(v0, pb0, o00, 0, 0, 0);
      o10 = __builtin_amdgcn_mfma_f32_16x16x32_bf16(v1, pb0, o10, 0, 0, 0);
      o01 = __builtin_amdgcn_mfma_f32_16x16x32_bf16(v0, pb1, o01, 0, 0, 0);
      o11 = __builtin_amdgcn_mfma_f32_16x16x32_bf16(v1, pb1, o11, 0, 0, 0);
    }
    __builtin_amdgcn_wave_barrier();
    __syncthreads();   // drains this step's prefetches (full phase elapsed)
  }
  rs0 += __shfl_xor(rs0, 16, 64); rs0 += __shfl_xor(rs0, 32, 64);
  rs1 += __shfl_xor(rs1, 16, 64); rs1 += __shfl_xor(rs1, 32, 64);
  const float i0 = 1.0f / rs0, i1 = 1.0f / rs1;
  // transpose O^T -> O rows via per-wave Ps scratch [32][72]
  ushort* Os = &Ps[wave][0][0];
  #pragma unroll
  for (int i = 0; i < 4; i++) {
    Os[l15 * 72 + quad * 4 + i]             = f2bff(o00[i] * i0);
    Os[l15 * 72 + 16 + quad * 4 + i]        = f2bff(o10[i] * i0);
    Os[(16 + l15) * 72 + quad * 4 + i]      = f2bff(o01[i] * i1);
    Os[(16 + l15) * 72 + 16 + quad * 4 + i] = f2bff(o11[i] * i1);
  }
  __builtin_amdgcn_wave_barrier();
  const int b = bh >> 3, h = bh & 7;
  #pragma unroll
  for (int pp = 0; pp < 2; pp++) {
    const int r = pp * 16 + (lane >> 2), seg = lane & 3;
    const short8 ov = *(const short8*)(Os + r * 72 + seg * 8);
    const int n = q0 + r;
    *(short8*)(out + ((size_t)(b * Nn + n)) * Dd + h * HDh + seg * 8) = ov;
  }
}

extern "C" void kernel_launch(void* const* d_in, const int* in_sizes, int n_in,
                              void* d_out, int out_size, void* d_ws, size_t ws_size,
                              hipStream_t stream)
{
  const float* x  = (const float*)d_in[0];
  const float* Wq = (const float*)d_in[1];
  const float* bq = (const float*)d_in[2];
  const float* Wk = (const float*)d_in[3];
  const float* bk = (const float*)d_in[4];
  const float* Wv = (const float*)d_in[5];
  const float* bv = (const float*)d_in[6];
  const float* Wo = (const float*)d_in[7];
  const float* bo = (const float*)d_in[8];
  const float* W1 = (const float*)d_in[9];
  const float* b1 = (const float*)d_in[10];
  const float* W2 = (const float*)d_in[11];
  const float* b2 = (const float*)d_in[12];

  char* ws = (char*)d_ws;
  ushort* wt    = (ushort*)ws;                       // 786432 bf16
  ushort* wtqkv = wt;
  ushort* wto   = wt + 196608;
  ushort* wt1   = wt + 262144;
  ushort* wt2   = wt + 524288;
  float*  bqkv  = (float*)(ws + 786432 * 2);
  ushort* s0    = (ushort*)(ws + 786432 * 2 + 4096); // 4 MiB slots
  ushort* s1    = s0 + Tt;                           // q [b,h,n,hd] (scaled)
  ushort* s2    = s1 + Tt;                           // k [b,h,n,hd]
  ushort* s3    = s2 + Tt;                           // v^T [b,h,hd,n]
  float*  xsk   = (float*)(s3 + Tt);                 // fp32 8 MiB
  ushort* xn2   = (ushort*)(xsk + Tt);               // bf16 4 MiB
  ushort* xn1   = s0;
  ushort* attn  = s0;                                // reuse (xn1 dead)
  ushort* hid   = s0;                                // 16 MiB spans s0..s3
  float*  outp  = (float*)d_out;

  const dim3 blk(256);
  hipLaunchKernelGGL(prep_kernel, dim3(193), blk, 0, stream,
                     Wq, Wk, Wv, Wo, W1, W2, bq, bk, bv, wt, bqkv);
  hipLaunchKernelGGL(ln_kernel, dim3(MT / 4), blk, 0, stream, x, xn1);
  hipLaunchKernelGGL((gemm_epi<0,128>), dim3(12, 64), blk, 0, stream,
                     xn1, wtqkv, bqkv, (const float*)nullptr, (void*)s1, 768, Dd);

  hipLaunchKernelGGL(attn_kernel, dim3(Nn / 128, Bb * Hh), blk, 0, stream,
                     s1, s2, s3, attn);

  hipLaunchKernelGGL((gemm_epi<1,64>), dim3(4, 128), blk, 0, stream,
                     attn, wto, bo, x, (void*)xsk, Dd, Dd);
  hipLaunchKernelGGL(ln_kernel, dim3(MT / 4), blk, 0, stream, xsk, xn2);
  hipLaunchKernelGGL((gemm_epi<2,128>), dim3(16, 64), blk, 0, stream,
                     xn2, wt1, b1, (const float*)nullptr, (void*)hid, DFFd, Dd);
  hipLaunchKernelGGL((gemm_epi<1,64>), dim3(4, 128), blk, 0, stream,
                     hid, wt2, b2, xsk, (void*)outp, Dd, DFFd);
}

// Round 8
// 201.622 us; speedup vs baseline: 1.7028x; 1.1493x over previous
//
#include <hip/hip_runtime.h>
#include <hip/hip_bf16.h>

// EncoderBlock: B=2, N=4096, D=256, H=8, HD=32, DFF=1024.
// I/O fp32; internal bf16 MFMA.
// Attention: split-K(4) flash with bf16 partial O + fp32 partial l (no
// atomics), q=64/wave, P round-trip in two 32-kv halves through a per-wave
// [64][40] LDS buffer, l accumulated via MFMA with a ones A-frag.
// GEMMs: BK=64 double-buffered gll16 with group-padded LDS tiles.
#define Bb 2
#define Nn 4096
#define Dd 256
#define Hh 8
#define HDh 32
#define DFFd 1024
#define MT (Bb*Nn)   // 8192 rows
#define Tt ((size_t)MT * Dd)
#define SPLIT 4
#define KVB (Nn / SPLIT)
#define NSTP (KVB / 64)   // 16

typedef __attribute__((ext_vector_type(8))) short short8;
typedef __attribute__((ext_vector_type(4))) float f32x4;
typedef __attribute__((address_space(1))) const unsigned int gu32;
typedef __attribute__((address_space(3))) unsigned int lu32;

__device__ __forceinline__ void gll16(const ushort* g, ushort* l) {
  // async global->LDS, 16B/lane; LDS dest = wave-uniform base + lane*16
  __builtin_amdgcn_global_load_lds((gu32*)g, (lu32*)l, 16, 0, 0);
}
__device__ __forceinline__ float bf2f(ushort u){
  union { unsigned int i; float f; } v; v.i = ((unsigned int)u) << 16; return v.f;
}
__device__ __forceinline__ ushort f2bf(float f){           // RNE
  union { float f; unsigned int i; } v; v.f = f;
  unsigned int r = v.i + 0x7fffu + ((v.i >> 16) & 1u);
  return (ushort)(r >> 16);
}
// group-padded LDS row offset: 64-ushort rows, +32 ushorts pad per 8 rows
__device__ __forceinline__ int ars(int r){ return r * 64 + (r >> 3) * 32; }

// ---- prep: LDS-tiled transpose fp32 W -> bf16 WT[n][k]; concat qkv bias ----
__global__ __launch_bounds__(256) void prep_kernel(
    const float* __restrict__ Wq, const float* __restrict__ Wk,
    const float* __restrict__ Wv, const float* __restrict__ Wo,
    const float* __restrict__ W1, const float* __restrict__ W2,
    const float* __restrict__ bq, const float* __restrict__ bk,
    const float* __restrict__ bv, ushort* __restrict__ wt,
    float* __restrict__ bqkv)
{
  const int bid = blockIdx.x, t = threadIdx.x;
  if (bid == 192) {
    bqkv[t] = bq[t]; bqkv[256 + t] = bk[t]; bqkv[512 + t] = bv[t];
    return;
  }
  __shared__ __align__(16) ushort T[64][72];
  const float* src; ushort* dst; int Nsrc, Kdst, kt, nt;
  if (bid < 64) {
    const int m = bid >> 4, tile = bid & 15;
    kt = tile >> 2; nt = tile & 3; Nsrc = 256; Kdst = 256;
    src = (m == 0 ? Wq : m == 1 ? Wk : m == 2 ? Wv : Wo);
    dst = (m == 3) ? (wt + 196608) : (wt + m * 65536);
  } else if (bid < 128) {
    const int tile = bid - 64; kt = tile >> 4; nt = tile & 15;
    Nsrc = 1024; Kdst = 256; src = W1; dst = wt + 262144;
  } else {
    const int tile = bid - 128; kt = tile >> 2; nt = tile & 3;
    Nsrc = 256; Kdst = 1024; src = W2; dst = wt + 524288;
  }
  const int k0 = kt * 64, n0 = nt * 64;
  const int cc = t & 15, rr = t >> 4;
  #pragma unroll
  for (int pass = 0; pass < 4; pass++) {
    const int k = rr + pass * 16;
    const float4 v = *(const float4*)(src + (size_t)(k0 + k) * Nsrc + n0 + cc * 4);
    T[cc * 4 + 0][k] = f2bf(v.x); T[cc * 4 + 1][k] = f2bf(v.y);
    T[cc * 4 + 2][k] = f2bf(v.z); T[cc * 4 + 3][k] = f2bf(v.w);
  }
  __syncthreads();
  const int nl = t >> 2, ks = (t & 3) * 16;
  const short8 a = *(const short8*)(&T[nl][ks]);
  const short8 b = *(const short8*)(&T[nl][ks + 8]);
  ushort* drow = dst + (size_t)(n0 + nl) * Kdst + k0 + ks;
  *(short8*)(drow) = a; *(short8*)(drow + 8) = b;
}

// ---- LayerNorm: (x-mean)/(std+1e-6); fp32 in, bf16 out; wave per row -------
__global__ __launch_bounds__(256) void ln_kernel(const float* __restrict__ x,
                                                 ushort* __restrict__ out)
{
  const int wave = threadIdx.x >> 6, lane = threadIdx.x & 63;
  const int row = blockIdx.x * 4 + wave;
  const float4 u = *(const float4*)(x + (size_t)row * Dd + lane * 4);
  float s1 = u.x + u.y + u.z + u.w;
  float s2 = u.x*u.x + u.y*u.y + u.z*u.z + u.w*u.w;
  #pragma unroll
  for (int m = 1; m < 64; m <<= 1) { s1 += __shfl_xor(s1, m, 64); s2 += __shfl_xor(s2, m, 64); }
  const float mean = s1 * (1.0f / Dd);
  float var = s2 * (1.0f / Dd) - mean * mean;
  var = var < 0.f ? 0.f : var;
  const float inv = 1.0f / (sqrtf(var) + 1e-6f);
  ushort4 o;
  o.x = f2bf((u.x - mean) * inv); o.y = f2bf((u.y - mean) * inv);
  o.z = f2bf((u.z - mean) * inv); o.w = f2bf((u.w - mean) * inv);
  *(ushort4*)(out + (size_t)row * Dd + lane * 4) = o;
}

// ---- BMx64-tile MFMA GEMM, BK=64 gll16 double-buffer -----------------------
// Loop: issue gll16(chunk c+1)->LDS[p^1]; compute chunk c (16*MI MFMA +
// 12 ds_read cover the vmcnt drain); barrier. LDS rows group-padded (ars)
// so frag reads stay at the b128 bank floor.
template<int EPI, int BM>
__global__ __launch_bounds__(256) void gemm_epi(
    const ushort* __restrict__ A, const ushort* __restrict__ BT,
    const float* __restrict__ bias, const float* __restrict__ res,
    void* __restrict__ outv, int N, int K)
{
  constexpr int MI = BM / 64;
  constexpr int AI = BM / 32;
  __shared__ __align__(16) ushort AsF[2][BM * 64 + (BM / 8) * 32];
  __shared__ __align__(16) ushort BsF[2][64 * 64 + 8 * 32];
  const int tid = threadIdx.x;
  const int wave = tid >> 6, lane = tid & 63;
  const int quad = lane >> 4, l15 = lane & 15;
  const int n0 = blockIdx.x * 64, m0 = blockIdx.y * BM;
  f32x4 acc[MI][4];
  #pragma unroll
  for (int mt = 0; mt < MI; mt++)
    #pragma unroll
    for (int nt = 0; nt < 4; nt++) acc[mt][nt] = (f32x4){0.f,0.f,0.f,0.f};
  const int srow = lane >> 3, scol = (lane & 7) * 8;
  const ushort* gA[AI];
  #pragma unroll
  for (int ai = 0; ai < AI; ai++)
    gA[ai] = A + (size_t)(m0 + ai * 32 + wave * 8 + srow) * K + scol;
  const ushort* gB[2];
  #pragma unroll
  for (int bi = 0; bi < 2; bi++)
    gB[bi] = BT + (size_t)(n0 + bi * 32 + wave * 8 + srow) * K + scol;
  int aoff[MI], boff[4];
  #pragma unroll
  for (int mt = 0; mt < MI; mt++) aoff[mt] = ars(wave * 16 * MI + mt * 16 + l15);
  #pragma unroll
  for (int nt = 0; nt < 4; nt++) boff[nt] = ars(nt * 16 + l15);
  // preamble: stage chunk 0
  #pragma unroll
  for (int ai = 0; ai < AI; ai++) gll16(gA[ai], &AsF[0][ars(ai * 32 + wave * 8)]);
  #pragma unroll
  for (int bi = 0; bi < 2; bi++) gll16(gB[bi], &BsF[0][ars(bi * 32 + wave * 8)]);
  __syncthreads();
  const int NC = K >> 6;
  int p = 0;
  for (int c = 0; c < NC; c++) {
    if (c + 1 < NC) {
      #pragma unroll
      for (int ai = 0; ai < AI; ai++)
        gll16(gA[ai] + (c + 1) * 64, &AsF[p ^ 1][ars(ai * 32 + wave * 8)]);
      #pragma unroll
      for (int bi = 0; bi < 2; bi++)
        gll16(gB[bi] + (c + 1) * 64, &BsF[p ^ 1][ars(bi * 32 + wave * 8)]);
    }
    #pragma unroll
    for (int kk = 0; kk < 2; kk++) {
      short8 af[MI];
      #pragma unroll
      for (int mt = 0; mt < MI; mt++)
        af[mt] = *(const short8*)(&AsF[p][aoff[mt] + kk * 32 + quad * 8]);
      #pragma unroll
      for (int nt = 0; nt < 4; nt++) {
        const short8 bf = *(const short8*)(&BsF[p][boff[nt] + kk * 32 + quad * 8]);
        #pragma unroll
        for (int mt = 0; mt < MI; mt++)
          acc[mt][nt] = __builtin_amdgcn_mfma_f32_16x16x32_bf16(af[mt], bf, acc[mt][nt], 0, 0, 0);
      }
    }
    __syncthreads();
    p ^= 1;
  }
  #pragma unroll
  for (int mt = 0; mt < MI; mt++) {
    const int row0 = m0 + wave * (16 * MI) + mt * 16 + quad * 4;
    #pragma unroll
    for (int nt = 0; nt < 4; nt++) {
      const int col = n0 + nt * 16 + l15;
      const float bv = bias[col];
      float c[4];
      #pragma unroll
      for (int i = 0; i < 4; i++) c[i] = acc[mt][nt][i] + bv;
      if (EPI == 0) {
        ushort* qkv = (ushort*)outv;
        const int w = col >> 8, cd = col & 255;
        const int h = cd >> 5, hd = cd & 31;
        const int b = row0 >> 12, n = row0 & (Nn - 1);
        if (w < 2) {
          const float sc2 = (w == 0) ? (1.4426950408889634f * 0.17677669529663687f) : 1.0f;
          ushort* dst = qkv + (size_t)w * Tt + ((size_t)((b * Hh + h) * Nn) + n) * HDh + hd;
          #pragma unroll
          for (int i = 0; i < 4; i++) dst[(size_t)i * HDh] = f2bf(c[i] * sc2);
        } else {   // V transposed: [b,h,hd,n]
          ushort4 pk;
          pk.x = f2bf(c[0]); pk.y = f2bf(c[1]); pk.z = f2bf(c[2]); pk.w = f2bf(c[3]);
          *(ushort4*)(qkv + 2 * Tt + ((size_t)((b * Hh + h) * HDh + hd)) * Nn + n) = pk;
        }
      } else if (EPI == 1) {
        float* out = (float*)outv;
        #pragma unroll
        for (int i = 0; i < 4; i++) {
          const size_t idx = (size_t)(row0 + i) * N + col;
          out[idx] = c[i] + res[idx];
        }
      } else {
        ushort* out = (ushort*)outv;
        #pragma unroll
        for (int i = 0; i < 4; i++) {
          const float t = tanhf(0.7978845608028654f * (c[i] + 0.044715f * c[i] * c[i] * c[i]));
          out[(size_t)(row0 + i) * N + col] = f2bf(0.5f * c[i] * (1.0f + t));
        }
      }
    }
  }
}

// ---- Flash attention: split-K(4), q=64/wave, bf16 partial O + fp32 l -------
__global__ __launch_bounds__(256, 4) void attn_kernel(
    const ushort* __restrict__ qp, const ushort* __restrict__ kp,
    const ushort* __restrict__ vtg, ushort* __restrict__ op0,
    ushort* __restrict__ op123, float* __restrict__ lp)
{
  __shared__ __align__(16) ushort Ks[2][64][32];   // K tile [kv][d] (gll16)
  __shared__ __align__(16) ushort Vt[2][32][72];   // V^T tile [d][kv] (reg-staged)
  __shared__ __align__(16) ushort Ps[4][64][40];   // per-wave P [q][kv-half]
  const int tid = threadIdx.x;
  const int wave = tid >> 6, lane = tid & 63;
  const int quad = lane >> 4, l15 = lane & 15;
  const int qtb = blockIdx.x, bh = blockIdx.y, sp = blockIdx.z;
  const size_t base = (size_t)bh * Nn * HDh;
  const int q0 = qtb * 256 + wave * 64;
  short8 qf[4];
  #pragma unroll
  for (int qt = 0; qt < 4; qt++)
    qf[qt] = *(const short8*)(qp + base + (size_t)(q0 + qt * 16 + l15) * HDh + quad * 8);
  const int kv0 = sp * KVB;
  const ushort* kg = kp + base + (size_t)(kv0 + wave * 16 + (lane >> 2)) * HDh + (lane & 3) * 8;
  const int vr = tid >> 3, vc = (tid & 7) * 8;
  const ushort* vg = vtg + base + (size_t)vr * Nn + kv0 + vc;
  ushort* psw = &Ps[wave][0][0];
  f32x4 o[2][4], ol[4];
  #pragma unroll
  for (int qt = 0; qt < 4; qt++) {
    o[0][qt] = (f32x4){0,0,0,0}; o[1][qt] = (f32x4){0,0,0,0};
    ol[qt] = (f32x4){0,0,0,0};
  }
  const short one = (short)0x3F80;
  const short8 ones = {one,one,one,one,one,one,one,one};
  const f32x4 zero4 = {0,0,0,0};
  // preamble: stage step 0; prefetch step1 V to regs
  gll16(kg, &Ks[0][wave * 16][0]);
  int4 vreg = *(const int4*)vg;
  *(int4*)(&Vt[0][vr][vc]) = vreg;
  vreg = *(const int4*)(vg + 64);
  __syncthreads();
  #pragma unroll 2
  for (int step = 0; step < NSTP; step++) {
    const int p = step & 1;
    if (step + 1 < NSTP) {
      gll16(kg + (size_t)(step + 1) * 64 * HDh, &Ks[p ^ 1][wave * 16][0]);
      *(int4*)(&Vt[p ^ 1][vr][vc]) = vreg;
    }
    if (step + 2 < NSTP) vreg = *(const int4*)(vg + (size_t)(step + 2) * 64);
    #pragma unroll
    for (int half = 0; half < 2; half++) {
      #pragma unroll
      for (int nt2 = 0; nt2 < 2; nt2++) {
        const int nt = half * 2 + nt2;
        const short8 kf = *(const short8*)(&Ks[p][nt * 16 + l15][quad * 8]);
        #pragma unroll
        for (int qt = 0; qt < 4; qt++) {
          const f32x4 s = __builtin_amdgcn_mfma_f32_16x16x32_bf16(kf, qf[qt], zero4, 0, 0, 0);
          const float p0 = __builtin_amdgcn_exp2f(s[0]);
          const float p1 = __builtin_amdgcn_exp2f(s[1]);
          const float p2 = __builtin_amdgcn_exp2f(s[2]);
          const float p3 = __builtin_amdgcn_exp2f(s[3]);
          uint2 pk;
          pk.x = __builtin_amdgcn_perm(__float_as_uint(p1) + 0x8000u,
                                       __float_as_uint(p0) + 0x8000u, 0x07060302u);
          pk.y = __builtin_amdgcn_perm(__float_as_uint(p3) + 0x8000u,
                                       __float_as_uint(p2) + 0x8000u, 0x07060302u);
          *(uint2*)(psw + (qt * 16 + l15) * 40 + nt2 * 16 + quad * 4) = pk;
        }
      }
      __builtin_amdgcn_wave_barrier();   // Ps wave-local; DS in-order per wave
      const short8 v0 = *(const short8*)(&Vt[p][l15][half * 32 + quad * 8]);
      const short8 v1 = *(const short8*)(&Vt[p][16 + l15][half * 32 + quad * 8]);
      #pragma unroll
      for (int qt = 0; qt < 4; qt++) {
        const short8 pb = *(const short8*)(psw + (qt * 16 + l15) * 40 + quad * 8);
        o[0][qt] = __builtin_amdgcn_mfma_f32_16x16x32_bf16(v0, pb, o[0][qt], 0, 0, 0);
        o[1][qt] = __builtin_amdgcn_mfma_f32_16x16x32_bf16(v1, pb, o[1][qt], 0, 0, 0);
        ol[qt]   = __builtin_amdgcn_mfma_f32_16x16x32_bf16(ones, pb, ol[qt], 0, 0, 0);
      }
      __builtin_amdgcn_wave_barrier();
    }
    __syncthreads();   // drains this step's prefetches (full phase elapsed)
  }
  // l partial: lane's ol[lane>>4][0] is exactly l(q0+lane)
  lp[(size_t)sp * (16 * Nn) + (size_t)bh * Nn + q0 + lane] = ol[lane >> 4][0];
  // O partial (unnormalized) -> bf16, transposed to [q][d] rows via psw
  ushort* ob = (sp == 0 ? op0 : op123 + (size_t)(sp - 1) * (16 * (size_t)Nn * HDh));
  #pragma unroll
  for (int pass = 0; pass < 2; pass++) {
    #pragma unroll
    for (int qt2 = 0; qt2 < 2; qt2++) {
      const int qt = pass * 2 + qt2;
      #pragma unroll
      for (int dt = 0; dt < 2; dt++) {
        ushort4 pk;
        pk.x = f2bf(o[dt][qt][0]); pk.y = f2bf(o[dt][qt][1]);
        pk.z = f2bf(o[dt][qt][2]); pk.w = f2bf(o[dt][qt][3]);
        *(ushort4*)(psw + (qt2 * 16 + l15) * 40 + dt * 16 + quad * 4) = pk;
      }
    }
    __builtin_amdgcn_wave_barrier();
    #pragma unroll
    for (int j = 0; j < 2; j++) {
      const int row = j * 16 + (lane >> 2);
      const short8 ov = *(const short8*)(psw + row * 40 + (lane & 3) * 8);
      const int q = q0 + pass * 32 + row;
      *(short8*)(ob + ((size_t)bh * Nn + q) * HDh + (lane & 3) * 8) = ov;
    }
    __builtin_amdgcn_wave_barrier();
  }
}

// ---- combine: O = (Σ_sp Opart) / (Σ_sp lpart), regather to [B,N,D] bf16 ----
__global__ __launch_bounds__(256) void attn_combine(
    const ushort* __restrict__ op0, const ushort* __restrict__ op123,
    const float* __restrict__ lp, ushort* __restrict__ attn)
{
  const int idx = blockIdx.x * 256 + threadIdx.x;   // 16bh x 4096n x 4(d8)
  const int d8 = idx & 3, n = (idx >> 2) & (Nn - 1), bh = idx >> 14;
  const size_t ln = (size_t)bh * Nn + n;
  float l = 0.f;
  #pragma unroll
  for (int sp = 0; sp < SPLIT; sp++) l += lp[(size_t)sp * (16 * Nn) + ln];
  const float inv = 1.0f / l;
  float acc[8];
  #pragma unroll
  for (int k = 0; k < 8; k++) acc[k] = 0.f;
  const size_t qoff = ln * HDh + d8 * 8;
  #pragma unroll
  for (int sp = 0; sp < SPLIT; sp++) {
    const ushort* src = (sp == 0 ? op0 : op123 + (size_t)(sp - 1) * (16 * (size_t)Nn * HDh)) + qoff;
    const short8 u = *(const short8*)src;
    #pragma unroll
    for (int k = 0; k < 8; k++) acc[k] += bf2f((ushort)u[k]);
  }
  short8 ov;
  #pragma unroll
  for (int k = 0; k < 8; k++) ov[k] = (short)f2bf(acc[k] * inv);
  const int b = bh >> 3, h = bh & 7;
  *(short8*)(attn + ((size_t)(b * Nn + n)) * Dd + h * HDh + d8 * 8) = ov;
}

extern "C" void kernel_launch(void* const* d_in, const int* in_sizes, int n_in,
                              void* d_out, int out_size, void* d_ws, size_t ws_size,
                              hipStream_t stream)
{
  const float* x  = (const float*)d_in[0];
  const float* Wq = (const float*)d_in[1];
  const float* bq = (const float*)d_in[2];
  const float* Wk = (const float*)d_in[3];
  const float* bk = (const float*)d_in[4];
  const float* Wv = (const float*)d_in[5];
  const float* bv = (const float*)d_in[6];
  const float* Wo = (const float*)d_in[7];
  const float* bo = (const float*)d_in[8];
  const float* W1 = (const float*)d_in[9];
  const float* b1 = (const float*)d_in[10];
  const float* W2 = (const float*)d_in[11];
  const float* b2 = (const float*)d_in[12];

  char* ws = (char*)d_ws;
  ushort* wt    = (ushort*)ws;                       // 786432 bf16
  ushort* wtqkv = wt;
  ushort* wto   = wt + 196608;
  ushort* wt1   = wt + 262144;
  ushort* wt2   = wt + 524288;
  float*  bqkv  = (float*)(ws + 786432 * 2);
  ushort* s0    = (ushort*)(ws + 786432 * 2 + 4096); // 4 MiB slots
  ushort* s1    = s0 + Tt;                           // q [b,h,n,hd] (scaled)
  ushort* s2    = s1 + Tt;                           // k [b,h,n,hd]
  ushort* s3    = s2 + Tt;                           // v^T [b,h,hd,n]
  float*  xsk   = (float*)(s3 + Tt);                 // fp32 8 MiB
  ushort* xn2   = (ushort*)(xsk + Tt);               // bf16 4 MiB
  ushort* xn1   = s0;
  ushort* hid   = s0;                                // 16 MiB spans s0..s3
  // attention scratch (lifetimes: between QKV and Wo):
  ushort* op0   = s0;                                // Opart sp0 (4 MiB, xn1 dead)
  ushort* op123 = (ushort*)xsk;                      // sp1..sp3 (12 MiB, xsk+xn2)
  float*  lp    = (float*)d_out;                     // 1 MiB of d_out (scratch)
  ushort* attnb = (ushort*)((char*)d_out + (4u << 20)); // 4 MiB of d_out
  float*  outp  = (float*)d_out;

  const dim3 blk(256);
  hipLaunchKernelGGL(prep_kernel, dim3(193), blk, 0, stream,
                     Wq, Wk, Wv, Wo, W1, W2, bq, bk, bv, wt, bqkv);
  hipLaunchKernelGGL(ln_kernel, dim3(MT / 4), blk, 0, stream, x, xn1);
  hipLaunchKernelGGL((gemm_epi<0,128>), dim3(12, 64), blk, 0, stream,
                     xn1, wtqkv, bqkv, (const float*)nullptr, (void*)s1, 768, Dd);

  hipLaunchKernelGGL(attn_kernel, dim3(Nn / 256, Bb * Hh, SPLIT), blk, 0, stream,
                     s1, s2, s3, op0, op123, lp);
  hipLaunchKernelGGL(attn_combine, dim3((Bb * Hh * Nn * 4) / 256), blk, 0, stream,
                     op0, op123, lp, attnb);

  hipLaunchKernelGGL((gemm_epi<1,64>), dim3(4, 128), blk, 0, stream,
                     attnb, wto, bo, x, (void*)xsk, Dd, Dd);
  hipLaunchKernelGGL(ln_kernel, dim3(MT / 4), blk, 0, stream, xsk, xn2);
  hipLaunchKernelGGL((gemm_epi<2,128>), dim3(16, 64), blk, 0, stream,
                     xn2, wt1, b1, (const float*)nullptr, (void*)hid, DFFd, Dd);
  hipLaunchKernelGGL((gemm_epi<1,64>), dim3(4, 128), blk, 0, stream,
                     hid, wt2, b2, xsk, (void*)outp, Dd, DFFd);
}